// Round 5
// baseline (140.029 us; speedup 1.0000x reference)
//
#include <hip/hip_runtime.h>
#include <math.h>

// ---- geometry ----
// Grid 50^3, coords shifted +1 -> occupy [1,50]. Dense key = (z*GY+y)*64+x.
// 8-deep z bricks probe z up to 57 -> z-dim 58.
#define GY 54
#define ZD 58
#define NROWS (ZD*GY*64)      // 200448 keys

// brick 8x4x8 = 256 output voxels per block; halo 10x6x10 = 600 rows
#define HX 10
#define HY 6
#define HXY 60                // halo rows per z-slice
#define NH 600
#define NBX 7
#define NBY 13
#define NBZ 7
#define NBRICK (NBX*NBY*NBZ)  // 637
#define SLAB 80               // ceil(637/8)

#define K3CC (27*64*64)       // 110592 weight elements

typedef __bf16  bf16x8 __attribute__((ext_vector_type(8)));
typedef float  f32x16 __attribute__((ext_vector_type(16)));

// global->LDS DMA, 16B per lane, linear LDS dest (wave-uniform base + lane*16)
#define AS1 __attribute__((address_space(1)))
#define AS3 __attribute__((address_space(3)))
#define GLD_LDS16(g, l) \
    __builtin_amdgcn_global_load_lds((const AS1 void*)(g), (AS3 void*)(l), 16, 0, 0)

// ---- fused prep: maps + reverse keys + Wt4 + feats->bf16 + zero row ----
__global__ void prep_kernel(const float* __restrict__ ipos, int n,
                            const float* __restrict__ opos, int m,
                            const float* __restrict__ vsp,
                            const float* __restrict__ W,
                            const float* __restrict__ feats,
                            int* __restrict__ imap, int* __restrict__ ikey,
                            int* __restrict__ omap, int* __restrict__ okey,
                            __bf16* __restrict__ Wt4,
                            __bf16* __restrict__ zrow,
                            __bf16* __restrict__ featsB) {
    int i = blockIdx.x * 256 + threadIdx.x;
    float vs = vsp[0];
    if (i < n) {
        int x = (int)floorf(ipos[3*i+0] / vs) + 1;
        int y = (int)floorf(ipos[3*i+1] / vs) + 1;
        int z = (int)floorf(ipos[3*i+2] / vs) + 1;
        int key = (z * GY + y) * 64 + x;
        ikey[i] = key;
        imap[key] = i;
    } else if (i < n + m) {
        int j = i - n;
        int x = (int)floorf(opos[3*j+0] / vs) + 1;
        int y = (int)floorf(opos[3*j+1] / vs) + 1;
        int z = (int)floorf(opos[3*j+2] / vs) + 1;
        int key = (z * GY + y) * 64 + x;
        okey[j] = key;
        omap[key] = j;
    } else if (i < n + m + K3CC) {
        int k  = i - n - m;
        int t  = k >> 12;
        int r  = k & 4095;
        int ci = r >> 6;
        int co = r & 63;
        int p   = ci >> 4;
        int cil = ci & 15;
        Wt4[(((p * 27 + t) << 6) + co) * 16 + cil] = (__bf16)W[k];
    } else if (i < n + m + K3CC + 32) {
        zrow[i - n - m - K3CC] = (__bf16)0.f;
    } else {
        int j = i - n - m - K3CC - 32;         // one bf16x8 chunk of featsB
        if (j < n * 8) {
            const float4* s = (const float4*)(feats + (size_t)j * 8);
            float4 f0 = s[0], f1 = s[1];
            bf16x8 v;
            v[0]=(__bf16)f0.x; v[1]=(__bf16)f0.y; v[2]=(__bf16)f0.z; v[3]=(__bf16)f0.w;
            v[4]=(__bf16)f1.x; v[5]=(__bf16)f1.y; v[6]=(__bf16)f1.z; v[7]=(__bf16)f1.w;
            *(bf16x8*)(featsB + (size_t)j * 8) = v;
        }
    }
}

// tap body: macro (NOT lambda -- by-ref capture demoted acc to scratch, r1).
// m-split: wave owns ONE z-slice -> 1 A-read + 2 B-reads + 2 MFMAs per tap.
// A from LDS; B straight from global (wave-uniform address across the block's
// 8 waves -> L1-hot after the first wave touches each tap's 2KB).
// SQ_LDS_BANK_CONFLICT tallies exactly 8/read = the wave64 b128 bandwidth
// floor (1024B / 128B-per-cy) -- NOT a fixable conflict; no swizzles.
#define TAP_BODY(t)                                                            \
    {                                                                          \
        const int drow = ((t)/9 - 1)*HXY + (((t)/3)%3 - 1)*HX + ((t)%3 - 1);   \
        bf16x8 a0 = *(const bf16x8*)(Ab0 + drow * 16);                         \
        bf16x8 b0 = *(const bf16x8*)(Bg0 + (t) * 1024);                        \
        bf16x8 b1 = *(const bf16x8*)(Bg0 + (t) * 1024 + 512);                  \
        acc0 = __builtin_amdgcn_mfma_f32_32x32x16_bf16(a0, b0, acc0, 0, 0, 0); \
        acc1 = __builtin_amdgcn_mfma_f32_32x32x16_bf16(a0, b1, acc1, 0, 0, 0); \
    }

// (512,2): never request min-waves that squeezes the allocator (two spill
// episodes with caps ~<=170 and a 64-reg acc). Acc is now 32 regs; natural
// allocation expected ~55-70 -> 4-8 waves/SIMD by VGPR; residency is
// grid-limited at ~2.5 blocks/CU x 8 waves = ~20 waves/CU.
__global__ __launch_bounds__(512, 2) void conv_kernel(
    const __bf16* __restrict__ featsB,  // [N,64] bf16
    const __bf16* __restrict__ Wt4,     // [4][27][64cout][16cin]
    const __bf16* __restrict__ zrow,    // 32 zero bf16
    const float* __restrict__ bias,     // [64]
    const int*   __restrict__ imap,
    const int*   __restrict__ ikey,
    const int*   __restrict__ omap,
    const int*   __restrict__ okey,
    float*       __restrict__ out,      // [M,64]
    int N, int M)
{
    __shared__ __align__(16) __bf16 halo[2 * NH * 16];        // 38400 B (double-buffered)
    __shared__ int ridx[NH];                                  //  2400 B
    __shared__ int obuf[256];                                 //  1024 B
    // total ~41.8 KB -> 3 blocks/CU by LDS (grid only supplies ~2.5)

    const int tid = threadIdx.x;

    // XCD slab swizzle
    int q = (blockIdx.x & 7) * SLAB + (blockIdx.x >> 3);
    if (q >= NBRICK) return;   // block-uniform exit before any barrier
    const int bx = q % NBX;
    int rem = q / NBX;
    const int by = rem % NBY;
    const int bz = rem / NBY;

    // ---- resolve halo row indices (validated) + output rows ----
    #pragma unroll
    for (int it = 0; it < 2; ++it) {
        int r = it * 512 + tid;
        if (r < NH) {
            int xs = r % HX;
            int t2 = r / HX;
            int ys = t2 % HY;
            int zs = t2 / HY;
            int key = ((bz*8 + zs) * GY + (by*4 + ys)) * 64 + (bx*8 + xs);
            int idx = imap[key];
            int c = min(max(idx, 0), N - 1);
            ridx[r] = (idx >= 0 && idx < N && ikey[c] == key) ? idx : -1;
        }
    }
    if (tid < 256) {
        int x = tid & 7, y = (tid >> 3) & 3, z = tid >> 5;
        int key = ((bz*8 + z + 1) * GY + (by*4 + y + 1)) * 64 + (bx*8 + x + 1);
        int o = omap[key];
        int c = min(max(o, 0), M - 1);
        obuf[tid] = (o >= 0 && o < M && okey[c] == key) ? o : -1;
    }

    // compute roles: wave w owns z-slice w (1 m-tile) x both n-tiles
    const int wave  = tid >> 6;
    const int lane  = tid & 63;
    const int lrow  = lane & 31;
    const int halfk = lane >> 5;
    const int xv = lrow & 7, yv = (lrow >> 3) & 3;
    const int arow0 = (wave + 1) * HXY + (yv + 1) * HX + (xv + 1);

    f32x16 acc0, acc1;
    #pragma unroll
    for (int i = 0; i < 16; ++i) { acc0[i]=0.f; acc1[i]=0.f; }

    __syncthreads();   // ridx + obuf visible

    // ---- prologue: DMA halo quarter p=0 into buf0 ----
    #pragma unroll
    for (int it = 0; it < 3; ++it) {
        int task = it * 512 + tid;
        if (task < NH * 2) {
            int r  = task >> 1;
            int hl = task & 1;
            int idx = ridx[r];
            const __bf16* src = (idx >= 0) ? featsB + (size_t)idx * 64 + hl * 8
                                           : zrow;
            GLD_LDS16(src, (char*)halo + task * 16);
        }
    }
    __syncthreads();   // compiler drains vmcnt(0) before s_barrier -> buf0 ready

    #pragma unroll 1
    for (int p = 0; p < 4; ++p) {
        // ---- issue next pass's halo DMA into the other buffer (overlaps taps) ----
        if (p < 3) {
            char* dst = (char*)halo + ((p + 1) & 1) * (NH * 16 * 2);
            #pragma unroll
            for (int it = 0; it < 3; ++it) {
                int task = it * 512 + tid;
                if (task < NH * 2) {
                    int r  = task >> 1;
                    int hl = task & 1;
                    int idx = ridx[r];
                    const __bf16* src = (idx >= 0)
                        ? featsB + (size_t)idx * 64 + (p + 1) * 16 + hl * 8
                        : zrow;
                    GLD_LDS16(src, dst + task * 16);
                }
            }
        }

        // ---- 27 taps: A from LDS buf[p&1], B from global (L1/L2-hot) ----
        const __bf16* Ab0 = halo + (p & 1) * (NH * 16) + arow0 * 16 + halfk * 8;
        const __bf16* Bg0 = Wt4 + (size_t)p * 27648 + lrow * 16 + halfk * 8;

        #pragma unroll
        for (int t = 0; t < 27; ++t) TAP_BODY(t)

        // one barrier: retires next-pass DMA (vmcnt drain) + closes this buffer
        if (p < 3) __syncthreads();
    }

    // ---- epilogue: C/D layout col=lane&31, row=(reg&3)+8*(reg>>2)+4*(lane>>5) ----
    const int col0 = lrow, col1 = 32 + lrow;
    const float bv0 = bias[col0], bv1 = bias[col1];
    #pragma unroll
    for (int r = 0; r < 16; ++r) {
        int mrow = (r & 3) + 8 * (r >> 2) + 4 * halfk;
        int o = obuf[wave * 32 + mrow];
        if (o >= 0) {
            out[(size_t)o * 64 + col0] = acc0[r] + bv0;
            out[(size_t)o * 64 + col1] = acc1[r] + bv1;
        }
    }
}

extern "C" void kernel_launch(void* const* d_in, const int* in_sizes, int n_in,
                              void* d_out, int out_size, void* d_ws, size_t ws_size,
                              hipStream_t stream) {
    const float* feats = (const float*)d_in[0];
    const float* ipos  = (const float*)d_in[1];
    const float* opos  = (const float*)d_in[2];
    const float* vsp   = (const float*)d_in[3];
    const float* W     = (const float*)d_in[4];
    const float* bias  = (const float*)d_in[5];

    int N = in_sizes[0] / 64;
    int M = out_size / 64;

    // workspace: imap | omap | ikey | okey | Wt4 | zrow | featsB (~15.5 MB)
    int*    imap   = (int*)d_ws;
    int*    omap   = imap + NROWS;
    int*    ikey   = omap + NROWS;
    int*    okey   = ikey + N;
    __bf16* Wt4    = (__bf16*)(okey + M);
    __bf16* zrow   = Wt4 + K3CC;
    __bf16* featsB = zrow + 32;

    int total = N + M + K3CC + 32 + N * 8;
    prep_kernel<<<(total + 255) / 256, 256, 0, stream>>>(ipos, N, opos, M, vsp, W, feats,
                                                         imap, ikey, omap, okey,
                                                         Wt4, zrow, featsB);
    conv_kernel<<<8 * SLAB, 512, 0, stream>>>(featsB, Wt4, zrow, bias,
                                              imap, ikey, omap, okey,
                                              (float*)d_out, N, M);
}